// Round 3
// baseline (183.253 us; speedup 1.0000x reference)
//
#include <hip/hip_runtime.h>

#define NGAUSS 2048
#define NPIX   65536
#define WID    512.0f
#define HEI    512.0f

// ---------------- tiled path geometry ----------------
#define NTX     8            // tiles in x (64 px each)
#define NTY     8
#define NTILE   (NTX * NTY)  // 64 tiles
#define TSHIFT  6            // 64 px per tile
#define GCAP    2048         // max gaussians per tile list (worst case = all)
#define PCAP    2048         // max pixels per tile (uniform avg 1024, max ~1150)
#define TPB     256
#define NCHUNK  (PCAP / TPB) // 8 pixel chunks per tile

// sqrt of exp2-domain cutoff: w < 2^-27 dropped; error <= 2048*2^-27 = 1.5e-5
#define SQRT_CUT 5.2f

// workspace layout (bytes)
#define WS_PRM_OFF   0                         // 2048*3 float4 = 98304 B
#define WS_GCNT_OFF  98304                     // 64 u32
#define WS_PCNT_OFF  98560                     // 64 u32
#define WS_GLIST_OFF 98816                     // 64*2048 u32 = 524288 B
#define WS_PLIST_OFF (98816 + 524288)          // 64*2048 u32 = 524288 B
#define WS_NEED      (WS_PLIST_OFF + 524288)   // 1,147,392 B

// Per-gaussian packed params (3 x float4 = 48 B):
// p0 = (A, B, C, D) ; p1 = (E0, E1, r, g) ; p2 = (b, 0, 0, 0)
// dx = A*X + B*Y + E0 ; dy = C*X + D*Y + E1 ; w = exp2(-(dx^2+dy^2))
// A..E pre-scaled by K = sqrt(log2(e)) so exp(-q) == exp2(-q_scaled).

// ---- kernel 1: per-gaussian prep + bbox -> tile gaussian lists ----
__global__ __launch_bounds__(256) void prep_kernel(
    const float* __restrict__ rgb, const float* __restrict__ mu,
    const float* __restrict__ scale, const float* __restrict__ angle,
    float4* __restrict__ prm, unsigned* __restrict__ gcount,
    unsigned* __restrict__ glist)
{
    const int n = blockIdx.x * TPB + threadIdx.x;   // grid covers exactly NGAUSS

    const float MU_BORDER = 1.05f;
    const float S_MIN = 1.0f / 30.0f;
    const float S_MAX = 1.0f / 0.75f;
    const float PI_APPROX = 3.1416f;
    const float K = 1.2011224087864498f;  // sqrt(log2(e))

    float mx = tanhf(mu[2*n+0]) * MU_BORDER * (0.5f * WID);
    float my = tanhf(mu[2*n+1]) * MU_BORDER * (0.5f * HEI);
    float al = tanhf(angle[n]) * PI_APPROX;
    float c = cosf(al);
    float s = sinf(al);
    float S0 = 1.0f / (1.0f + expf(-scale[2*n+0])) * (S_MAX - S_MIN) + S_MIN;
    float S1 = 1.0f / (1.0f + expf(-scale[2*n+1])) * (S_MAX - S_MIN) + S_MIN;

    float A  =  S0 * c * K;
    float Bc = -(S0 * s * K);
    float C  =  S1 * s * K;
    float D  =  S1 * c * K;
    float E0 = -(A * mx + Bc * my);
    float E1 = -(C * mx + D  * my);

    float r = 1.0f / (1.0f + expf(-rgb[3*n+0]));
    float g = 1.0f / (1.0f + expf(-rgb[3*n+1]));
    float b = 1.0f / (1.0f + expf(-rgb[3*n+2]));

    prm[3*n + 0] = make_float4(A, Bc, C, D);
    prm[3*n + 1] = make_float4(E0, E1, r, g);
    prm[3*n + 2] = make_float4(b, 0.f, 0.f, 0.f);

    // conservative bbox of {q_scaled <= SQRT_CUT^2}: ellipse projections
    // max|vx| = sqrtT/K * sqrt(c^2/S0^2 + s^2/S1^2), sim. for vy
    float i0 = 1.0f / S0, i1 = 1.0f / S1;
    float hx = (SQRT_CUT / K) * sqrtf(c*c*i0*i0 + s*s*i1*i1);
    float hy = (SQRT_CUT / K) * sqrtf(s*s*i0*i0 + c*c*i1*i1);
    float px = mx + 0.5f * WID;   // pixel-space center
    float py = my + 0.5f * HEI;

    int ix0 = (int)floorf(px - hx), ix1 = (int)floorf(px + hx);
    int iy0 = (int)floorf(py - hy), iy1 = (int)floorf(py + hy);
    int tx0 = max(0, ix0 >> TSHIFT), tx1 = min(NTX - 1, ix1 >> TSHIFT);
    int ty0 = max(0, iy0 >> TSHIFT), ty1 = min(NTY - 1, iy1 >> TSHIFT);

    for (int ty = ty0; ty <= ty1; ++ty)
        for (int tx = tx0; tx <= tx1; ++tx) {
            int t = ty * NTX + tx;
            unsigned idx = atomicAdd(&gcount[t], 1u);
            glist[t * GCAP + idx] = (unsigned)n;   // idx < 2048 always
        }
}

// ---- kernel 2: pixel -> tile lists ----
__global__ __launch_bounds__(256) void bin_kernel(
    const float2* __restrict__ x, unsigned* __restrict__ pcount,
    unsigned* __restrict__ plist)
{
    const int b = blockIdx.x * TPB + threadIdx.x;   // grid covers exactly NPIX
    float2 p = x[b];
    int tx = min(NTX - 1, max(0, ((int)p.x) >> TSHIFT));
    int ty = min(NTY - 1, max(0, ((int)p.y) >> TSHIFT));
    int t = ty * NTX + tx;
    unsigned idx = atomicAdd(&pcount[t], 1u);
    if (idx < PCAP) plist[t * PCAP + idx] = (unsigned)b;
}

// ---- kernel 3: per-tile splat; one thread = one pixel; plain stores ----
__global__ __launch_bounds__(256) void splat_tile(
    const float2* __restrict__ x, const float4* __restrict__ prm,
    const unsigned* __restrict__ gcount, const unsigned* __restrict__ glist,
    const unsigned* __restrict__ pcount, const unsigned* __restrict__ plist,
    float* __restrict__ out)
{
    __shared__ float4 sg[TPB * 3];   // 12 KiB: one batch of gaussian params

    const int t     = blockIdx.x;
    const int tid   = threadIdx.x;
    const unsigned pcnt = pcount[t];
    const unsigned base = blockIdx.y * TPB;
    if (base >= pcnt) return;                 // uniform exit, before barriers

    const bool valid = (base + tid) < pcnt;
    unsigned slot = base + (valid ? (unsigned)tid : 0u);
    unsigned pid  = plist[t * PCAP + slot];
    float2 p = x[pid];
    float X = p.x - 0.5f * WID;
    float Y = p.y - 0.5f * HEI;

    const unsigned gcnt = gcount[t];
    float ar = 0.f, ag = 0.f, ab = 0.f;

    for (unsigned g0 = 0; g0 < gcnt; g0 += TPB) {
        __syncthreads();
        unsigned gi = g0 + tid;
        if (gi < gcnt) {
            unsigned n = glist[t * GCAP + gi];
            sg[3*tid + 0] = prm[3*n + 0];
            sg[3*tid + 1] = prm[3*n + 1];
            sg[3*tid + 2] = prm[3*n + 2];
        }
        __syncthreads();

        unsigned cnt = min((unsigned)TPB, gcnt - g0);
        #pragma unroll 4
        for (unsigned j = 0; j < cnt; ++j) {
            float4 c0 = sg[3*j + 0];
            float4 c1 = sg[3*j + 1];
            float4 c2 = sg[3*j + 2];
            float dx = fmaf(c0.x, X, fmaf(c0.y, Y, c1.x));
            float dy = fmaf(c0.z, X, fmaf(c0.w, Y, c1.y));
            float q  = fmaf(dx, dx, dy * dy);
            float w  = __builtin_amdgcn_exp2f(-q);
            ar = fmaf(w, c1.z, ar);
            ag = fmaf(w, c1.w, ag);
            ab = fmaf(w, c2.x, ab);
        }
    }

    if (valid) {                 // exactly one writer per pixel -> no atomics
        out[3*pid + 0] = ar;
        out[3*pid + 1] = ag;
        out[3*pid + 2] = ab;
    }
}

// ---------------- fallback: round-2 flat kernel (ws too small) ----------------
#define NSLICE 16
#define GPB    (NGAUSS / NSLICE)
#define PPB    512

__global__ __launch_bounds__(256) void splat_flat(
    const float2* __restrict__ x, const float* __restrict__ rgb,
    const float* __restrict__ mu, const float* __restrict__ scale,
    const float* __restrict__ angle, float* __restrict__ out)
{
    __shared__ float4 sh4[GPB * 2];
    __shared__ float  shb[GPB];

    const int slice = blockIdx.x & (NSLICE - 1);
    const int pg    = blockIdx.x >> 4;
    const int tid   = threadIdx.x;

    if (tid < GPB) {
        const float MU_BORDER = 1.05f;
        const float S_MIN = 1.0f / 30.0f;
        const float S_MAX = 1.0f / 0.75f;
        const float PI_APPROX = 3.1416f;
        const float K = 1.2011224087864498f;

        int n = slice * GPB + tid;
        float mx = tanhf(mu[2*n+0]) * MU_BORDER * (0.5f * WID);
        float my = tanhf(mu[2*n+1]) * MU_BORDER * (0.5f * HEI);
        float al = tanhf(angle[n]) * PI_APPROX;
        float c = cosf(al);
        float s = sinf(al);
        float S0 = 1.0f / (1.0f + expf(-scale[2*n+0])) * (S_MAX - S_MIN) + S_MIN;
        float S1 = 1.0f / (1.0f + expf(-scale[2*n+1])) * (S_MAX - S_MIN) + S_MIN;
        float A  =  S0 * c * K;
        float Bc = -(S0 * s * K);
        float C  =  S1 * s * K;
        float D  =  S1 * c * K;
        sh4[2*tid + 0] = make_float4(A, Bc, C, D);
        sh4[2*tid + 1] = make_float4(-(A * mx + Bc * my), -(C * mx + D * my),
                                     1.0f / (1.0f + expf(-rgb[3*n+0])),
                                     1.0f / (1.0f + expf(-rgb[3*n+1])));
        shb[tid] = 1.0f / (1.0f + expf(-rgb[3*n+2]));
    }
    __syncthreads();

    const int t0 = pg * PPB + tid;
    const int t1 = t0 + TPB;
    float2 xy0 = x[t0];
    float2 xy1 = x[t1];
    float X0 = xy0.x - 0.5f * WID, Y0 = xy0.y - 0.5f * HEI;
    float X1 = xy1.x - 0.5f * WID, Y1 = xy1.y - 0.5f * HEI;

    float ar0 = 0.f, ag0 = 0.f, ab0 = 0.f;
    float ar1 = 0.f, ag1 = 0.f, ab1 = 0.f;
    #pragma unroll 4
    for (int j = 0; j < GPB; ++j) {
        float4 c0 = sh4[2*j + 0];
        float4 c1 = sh4[2*j + 1];
        float bb  = shb[j];
        float dx0 = fmaf(c0.x, X0, fmaf(c0.y, Y0, c1.x));
        float dy0 = fmaf(c0.z, X0, fmaf(c0.w, Y0, c1.y));
        float w0  = __builtin_amdgcn_exp2f(-fmaf(dx0, dx0, dy0 * dy0));
        float dx1 = fmaf(c0.x, X1, fmaf(c0.y, Y1, c1.x));
        float dy1 = fmaf(c0.z, X1, fmaf(c0.w, Y1, c1.y));
        float w1  = __builtin_amdgcn_exp2f(-fmaf(dx1, dx1, dy1 * dy1));
        ar0 = fmaf(w0, c1.z, ar0); ag0 = fmaf(w0, c1.w, ag0); ab0 = fmaf(w0, bb, ab0);
        ar1 = fmaf(w1, c1.z, ar1); ag1 = fmaf(w1, c1.w, ag1); ab1 = fmaf(w1, bb, ab1);
    }

    atomicAdd(&out[3*t0 + 0], ar0);
    atomicAdd(&out[3*t0 + 1], ag0);
    atomicAdd(&out[3*t0 + 2], ab0);
    atomicAdd(&out[3*t1 + 0], ar1);
    atomicAdd(&out[3*t1 + 1], ag1);
    atomicAdd(&out[3*t1 + 2], ab1);
}

extern "C" void kernel_launch(void* const* d_in, const int* in_sizes, int n_in,
                              void* d_out, int out_size, void* d_ws, size_t ws_size,
                              hipStream_t stream) {
    const float* x     = (const float*)d_in[0];  // [B,2]
    const float* rgb   = (const float*)d_in[1];  // [N,3]
    const float* mu    = (const float*)d_in[2];  // [N,2]
    const float* scale = (const float*)d_in[3];  // [N,2]
    const float* angle = (const float*)d_in[4];  // [N]

    // harness poisons d_out with 0xAA — zero it (async, graph-capture safe)
    hipMemsetAsync(d_out, 0, (size_t)out_size * sizeof(float), stream);

    if (ws_size >= (size_t)WS_NEED && d_ws != nullptr) {
        char* ws = (char*)d_ws;
        float4*   prm    = (float4*)(ws + WS_PRM_OFF);
        unsigned* gcount = (unsigned*)(ws + WS_GCNT_OFF);
        unsigned* pcount = (unsigned*)(ws + WS_PCNT_OFF);
        unsigned* glist  = (unsigned*)(ws + WS_GLIST_OFF);
        unsigned* plist  = (unsigned*)(ws + WS_PLIST_OFF);

        // zero the two count arrays (contiguous 512 B)
        hipMemsetAsync(ws + WS_GCNT_OFF, 0, 512, stream);

        hipLaunchKernelGGL(prep_kernel, dim3(NGAUSS / TPB), dim3(TPB), 0, stream,
                           rgb, mu, scale, angle, prm, gcount, glist);
        hipLaunchKernelGGL(bin_kernel, dim3(NPIX / TPB), dim3(TPB), 0, stream,
                           (const float2*)x, pcount, plist);
        hipLaunchKernelGGL(splat_tile, dim3(NTILE, NCHUNK), dim3(TPB), 0, stream,
                           (const float2*)x, prm, gcount, glist, pcount, plist,
                           (float*)d_out);
    } else {
        hipLaunchKernelGGL(splat_flat, dim3(NPIX / PPB * NSLICE), dim3(TPB), 0, stream,
                           (const float2*)x, rgb, mu, scale, angle, (float*)d_out);
    }
}

// Round 4
// 82.074 us; speedup vs baseline: 2.2328x; 2.2328x over previous
//
#include <hip/hip_runtime.h>

#define NGAUSS 2048
#define NPIX   65536
#define WID    512.0f
#define HEI    512.0f

// ---------------- tiled path geometry ----------------
#define NTX     8            // tiles in x (64 px each)
#define NTY     8
#define NTILE   (NTX * NTY)  // 64 tiles
#define TSHIFT  6            // 64 px per tile
#define GCAP    2048         // max gaussians per tile list (worst case = all)
#define PCAP    2048         // max pixels per tile (uniform avg 1024, max ~1200)
#define TPB     256
#define NCHUNK  (PCAP / TPB) // 8 pixel chunks per tile
#define BIN_NB  64           // bin blocks; each handles NPIX/BIN_NB pixels
#define BIN_PPB (NPIX / BIN_NB)      // 1024
#define BIN_PPT (BIN_PPB / TPB)      // 4 pixels per thread

// sqrt of exp2-domain cutoff: w < 2^-27 dropped; error <= 2048*2^-27 = 1.5e-5
#define SQRT_CUT 5.2f

// workspace layout (bytes)
#define WS_PRM_OFF   0                         // 2048*3 float4 = 98304 B
#define WS_GCNT_OFF  98304                     // 64 u32
#define WS_PCNT_OFF  98560                     // 64 u32
#define WS_GLIST_OFF 98816                     // 64*2048 u32 = 524288 B
#define WS_PLIST_OFF (98816 + 524288)          // 64*2048 u32 = 524288 B
#define WS_NEED      (WS_PLIST_OFF + 524288)   // 1,147,392 B

// Per-gaussian packed params (3 x float4 = 48 B):
// p0 = (A, B, C, D) ; p1 = (E0, E1, r, g) ; p2 = (b, 0, 0, 0)
// dx = A*X + B*Y + E0 ; dy = C*X + D*Y + E1 ; w = exp2(-(dx^2+dy^2))
// A..E pre-scaled by K = sqrt(log2(e)) so exp(-q) == exp2(-q_scaled).

// ---- kernel 1: per-gaussian prep + bbox -> tile gaussian lists ----
// Block-privatized binning: LDS histogram, ONE global atomic per (block,tile)
// to reserve a contiguous range, then LDS slot allocation. Avoids the
// 100us same-address atomic serialization measured in round 3.
__global__ __launch_bounds__(256) void prep_kernel(
    const float* __restrict__ rgb, const float* __restrict__ mu,
    const float* __restrict__ scale, const float* __restrict__ angle,
    float4* __restrict__ prm, unsigned* __restrict__ gcount,
    unsigned* __restrict__ glist)
{
    __shared__ unsigned lcnt[NTILE];
    __shared__ unsigned lbase[NTILE];

    const int tid = threadIdx.x;
    const int n   = blockIdx.x * TPB + tid;   // grid covers exactly NGAUSS

    if (tid < NTILE) lcnt[tid] = 0u;

    const float MU_BORDER = 1.05f;
    const float S_MIN = 1.0f / 30.0f;
    const float S_MAX = 1.0f / 0.75f;
    const float PI_APPROX = 3.1416f;
    const float K = 1.2011224087864498f;  // sqrt(log2(e))

    float mx = tanhf(mu[2*n+0]) * MU_BORDER * (0.5f * WID);
    float my = tanhf(mu[2*n+1]) * MU_BORDER * (0.5f * HEI);
    float al = tanhf(angle[n]) * PI_APPROX;
    float c = cosf(al);
    float s = sinf(al);
    float S0 = 1.0f / (1.0f + expf(-scale[2*n+0])) * (S_MAX - S_MIN) + S_MIN;
    float S1 = 1.0f / (1.0f + expf(-scale[2*n+1])) * (S_MAX - S_MIN) + S_MIN;

    float A  =  S0 * c * K;
    float Bc = -(S0 * s * K);
    float C  =  S1 * s * K;
    float D  =  S1 * c * K;
    float E0 = -(A * mx + Bc * my);
    float E1 = -(C * mx + D  * my);

    float r = 1.0f / (1.0f + expf(-rgb[3*n+0]));
    float g = 1.0f / (1.0f + expf(-rgb[3*n+1]));
    float b = 1.0f / (1.0f + expf(-rgb[3*n+2]));

    prm[3*n + 0] = make_float4(A, Bc, C, D);
    prm[3*n + 1] = make_float4(E0, E1, r, g);
    prm[3*n + 2] = make_float4(b, 0.f, 0.f, 0.f);

    // conservative bbox of {q_scaled <= SQRT_CUT^2}: ellipse projections
    float i0 = 1.0f / S0, i1 = 1.0f / S1;
    float hx = (SQRT_CUT / K) * sqrtf(c*c*i0*i0 + s*s*i1*i1);
    float hy = (SQRT_CUT / K) * sqrtf(s*s*i0*i0 + c*c*i1*i1);
    float px = mx + 0.5f * WID;   // pixel-space center
    float py = my + 0.5f * HEI;

    int ix0 = (int)floorf(px - hx), ix1 = (int)floorf(px + hx);
    int iy0 = (int)floorf(py - hy), iy1 = (int)floorf(py + hy);
    int tx0 = max(0, ix0 >> TSHIFT), tx1 = min(NTX - 1, ix1 >> TSHIFT);
    int ty0 = max(0, iy0 >> TSHIFT), ty1 = min(NTY - 1, iy1 >> TSHIFT);

    __syncthreads();
    // pass 1: LDS histogram
    for (int ty = ty0; ty <= ty1; ++ty)
        for (int tx = tx0; tx <= tx1; ++tx)
            atomicAdd(&lcnt[ty * NTX + tx], 1u);
    __syncthreads();
    // reserve global ranges (8 blocks -> chains of 8 per tile counter)
    if (tid < NTILE) {
        lbase[tid] = atomicAdd(&gcount[tid], lcnt[tid]);
        lcnt[tid] = 0u;
    }
    __syncthreads();
    // pass 2: LDS slot allocation + scatter
    for (int ty = ty0; ty <= ty1; ++ty)
        for (int tx = tx0; tx <= tx1; ++tx) {
            int t = ty * NTX + tx;
            unsigned slot = lbase[t] + atomicAdd(&lcnt[t], 1u);
            if (slot < GCAP) glist[t * GCAP + slot] = (unsigned)n;
        }
}

// ---- kernel 2: pixel -> tile lists (block-privatized, same scheme) ----
__global__ __launch_bounds__(256) void bin_kernel(
    const float2* __restrict__ x, unsigned* __restrict__ pcount,
    unsigned* __restrict__ plist)
{
    __shared__ unsigned lcnt[NTILE];
    __shared__ unsigned lbase[NTILE];

    const int tid   = threadIdx.x;
    const int start = blockIdx.x * BIN_PPB;

    if (tid < NTILE) lcnt[tid] = 0u;
    __syncthreads();

    unsigned tcache[BIN_PPT];
    #pragma unroll
    for (int k = 0; k < BIN_PPT; ++k) {
        int b = start + k * TPB + tid;
        float2 p = x[b];
        int tx = min(NTX - 1, max(0, ((int)p.x) >> TSHIFT));
        int ty = min(NTY - 1, max(0, ((int)p.y) >> TSHIFT));
        unsigned t = (unsigned)(ty * NTX + tx);
        tcache[k] = t;
        atomicAdd(&lcnt[t], 1u);            // LDS atomic
    }
    __syncthreads();
    if (tid < NTILE) {
        lbase[tid] = atomicAdd(&pcount[tid], lcnt[tid]);   // 64 chains of 64
        lcnt[tid] = 0u;
    }
    __syncthreads();
    #pragma unroll
    for (int k = 0; k < BIN_PPT; ++k) {
        int b = start + k * TPB + tid;
        unsigned t = tcache[k];
        unsigned slot = lbase[t] + atomicAdd(&lcnt[t], 1u);
        if (slot < PCAP) plist[t * PCAP + slot] = (unsigned)b;
    }
}

// ---- kernel 3: per-tile splat; one thread = one pixel; plain stores ----
__global__ __launch_bounds__(256) void splat_tile(
    const float2* __restrict__ x, const float4* __restrict__ prm,
    const unsigned* __restrict__ gcount, const unsigned* __restrict__ glist,
    const unsigned* __restrict__ pcount, const unsigned* __restrict__ plist,
    float* __restrict__ out)
{
    __shared__ float4 sg[TPB * 3];   // 12 KiB: one batch of gaussian params

    const int t     = blockIdx.x;
    const int tid   = threadIdx.x;
    const unsigned pcnt = min(pcount[t], (unsigned)PCAP);
    const unsigned base = blockIdx.y * TPB;
    if (base >= pcnt) return;                 // uniform exit, before barriers

    const bool valid = (base + tid) < pcnt;
    unsigned slot = base + (valid ? (unsigned)tid : 0u);
    unsigned pid  = plist[t * PCAP + slot];
    float2 p = x[pid];
    float X = p.x - 0.5f * WID;
    float Y = p.y - 0.5f * HEI;

    const unsigned gcnt = min(gcount[t], (unsigned)GCAP);
    float ar = 0.f, ag = 0.f, ab = 0.f;

    for (unsigned g0 = 0; g0 < gcnt; g0 += TPB) {
        __syncthreads();
        unsigned gi = g0 + tid;
        if (gi < gcnt) {
            unsigned n = glist[t * GCAP + gi];
            sg[3*tid + 0] = prm[3*n + 0];
            sg[3*tid + 1] = prm[3*n + 1];
            sg[3*tid + 2] = prm[3*n + 2];
        }
        __syncthreads();

        unsigned cnt = min((unsigned)TPB, gcnt - g0);
        #pragma unroll 4
        for (unsigned j = 0; j < cnt; ++j) {
            float4 c0 = sg[3*j + 0];
            float4 c1 = sg[3*j + 1];
            float4 c2 = sg[3*j + 2];
            float dx = fmaf(c0.x, X, fmaf(c0.y, Y, c1.x));
            float dy = fmaf(c0.z, X, fmaf(c0.w, Y, c1.y));
            float q  = fmaf(dx, dx, dy * dy);
            float w  = __builtin_amdgcn_exp2f(-q);
            ar = fmaf(w, c1.z, ar);
            ag = fmaf(w, c1.w, ag);
            ab = fmaf(w, c2.x, ab);
        }
    }

    if (valid) {                 // exactly one writer per pixel -> no atomics
        out[3*pid + 0] = ar;
        out[3*pid + 1] = ag;
        out[3*pid + 2] = ab;
    }
}

// ---------------- fallback: round-2 flat kernel (ws too small) ----------------
#define NSLICE 16
#define GPB    (NGAUSS / NSLICE)
#define PPB    512

__global__ __launch_bounds__(256) void splat_flat(
    const float2* __restrict__ x, const float* __restrict__ rgb,
    const float* __restrict__ mu, const float* __restrict__ scale,
    const float* __restrict__ angle, float* __restrict__ out)
{
    __shared__ float4 sh4[GPB * 2];
    __shared__ float  shb[GPB];

    const int slice = blockIdx.x & (NSLICE - 1);
    const int pg    = blockIdx.x >> 4;
    const int tid   = threadIdx.x;

    if (tid < GPB) {
        const float MU_BORDER = 1.05f;
        const float S_MIN = 1.0f / 30.0f;
        const float S_MAX = 1.0f / 0.75f;
        const float PI_APPROX = 3.1416f;
        const float K = 1.2011224087864498f;

        int n = slice * GPB + tid;
        float mx = tanhf(mu[2*n+0]) * MU_BORDER * (0.5f * WID);
        float my = tanhf(mu[2*n+1]) * MU_BORDER * (0.5f * HEI);
        float al = tanhf(angle[n]) * PI_APPROX;
        float c = cosf(al);
        float s = sinf(al);
        float S0 = 1.0f / (1.0f + expf(-scale[2*n+0])) * (S_MAX - S_MIN) + S_MIN;
        float S1 = 1.0f / (1.0f + expf(-scale[2*n+1])) * (S_MAX - S_MIN) + S_MIN;
        float A  =  S0 * c * K;
        float Bc = -(S0 * s * K);
        float C  =  S1 * s * K;
        float D  =  S1 * c * K;
        sh4[2*tid + 0] = make_float4(A, Bc, C, D);
        sh4[2*tid + 1] = make_float4(-(A * mx + Bc * my), -(C * mx + D * my),
                                     1.0f / (1.0f + expf(-rgb[3*n+0])),
                                     1.0f / (1.0f + expf(-rgb[3*n+1])));
        shb[tid] = 1.0f / (1.0f + expf(-rgb[3*n+2]));
    }
    __syncthreads();

    const int t0 = pg * PPB + tid;
    const int t1 = t0 + TPB;
    float2 xy0 = x[t0];
    float2 xy1 = x[t1];
    float X0 = xy0.x - 0.5f * WID, Y0 = xy0.y - 0.5f * HEI;
    float X1 = xy1.x - 0.5f * WID, Y1 = xy1.y - 0.5f * HEI;

    float ar0 = 0.f, ag0 = 0.f, ab0 = 0.f;
    float ar1 = 0.f, ag1 = 0.f, ab1 = 0.f;
    #pragma unroll 4
    for (int j = 0; j < GPB; ++j) {
        float4 c0 = sh4[2*j + 0];
        float4 c1 = sh4[2*j + 1];
        float bb  = shb[j];
        float dx0 = fmaf(c0.x, X0, fmaf(c0.y, Y0, c1.x));
        float dy0 = fmaf(c0.z, X0, fmaf(c0.w, Y0, c1.y));
        float w0  = __builtin_amdgcn_exp2f(-fmaf(dx0, dx0, dy0 * dy0));
        float dx1 = fmaf(c0.x, X1, fmaf(c0.y, Y1, c1.x));
        float dy1 = fmaf(c0.z, X1, fmaf(c0.w, Y1, c1.y));
        float w1  = __builtin_amdgcn_exp2f(-fmaf(dx1, dx1, dy1 * dy1));
        ar0 = fmaf(w0, c1.z, ar0); ag0 = fmaf(w0, c1.w, ag0); ab0 = fmaf(w0, bb, ab0);
        ar1 = fmaf(w1, c1.z, ar1); ag1 = fmaf(w1, c1.w, ag1); ab1 = fmaf(w1, bb, ab1);
    }

    atomicAdd(&out[3*t0 + 0], ar0);
    atomicAdd(&out[3*t0 + 1], ag0);
    atomicAdd(&out[3*t0 + 2], ab0);
    atomicAdd(&out[3*t1 + 0], ar1);
    atomicAdd(&out[3*t1 + 1], ag1);
    atomicAdd(&out[3*t1 + 2], ab1);
}

extern "C" void kernel_launch(void* const* d_in, const int* in_sizes, int n_in,
                              void* d_out, int out_size, void* d_ws, size_t ws_size,
                              hipStream_t stream) {
    const float* x     = (const float*)d_in[0];  // [B,2]
    const float* rgb   = (const float*)d_in[1];  // [N,3]
    const float* mu    = (const float*)d_in[2];  // [N,2]
    const float* scale = (const float*)d_in[3];  // [N,2]
    const float* angle = (const float*)d_in[4];  // [N]

    // harness poisons d_out with 0xAA — zero it (async, graph-capture safe)
    hipMemsetAsync(d_out, 0, (size_t)out_size * sizeof(float), stream);

    if (ws_size >= (size_t)WS_NEED && d_ws != nullptr) {
        char* ws = (char*)d_ws;
        float4*   prm    = (float4*)(ws + WS_PRM_OFF);
        unsigned* gcount = (unsigned*)(ws + WS_GCNT_OFF);
        unsigned* pcount = (unsigned*)(ws + WS_PCNT_OFF);
        unsigned* glist  = (unsigned*)(ws + WS_GLIST_OFF);
        unsigned* plist  = (unsigned*)(ws + WS_PLIST_OFF);

        // zero the two count arrays (contiguous 512 B)
        hipMemsetAsync(ws + WS_GCNT_OFF, 0, 512, stream);

        hipLaunchKernelGGL(prep_kernel, dim3(NGAUSS / TPB), dim3(TPB), 0, stream,
                           rgb, mu, scale, angle, prm, gcount, glist);
        hipLaunchKernelGGL(bin_kernel, dim3(BIN_NB), dim3(TPB), 0, stream,
                           (const float2*)x, pcount, plist);
        hipLaunchKernelGGL(splat_tile, dim3(NTILE, NCHUNK), dim3(TPB), 0, stream,
                           (const float2*)x, prm, gcount, glist, pcount, plist,
                           (float*)d_out);
    } else {
        hipLaunchKernelGGL(splat_flat, dim3(NPIX / PPB * NSLICE), dim3(TPB), 0, stream,
                           (const float2*)x, rgb, mu, scale, angle, (float*)d_out);
    }
}

// Round 5
// 75.694 us; speedup vs baseline: 2.4210x; 1.0843x over previous
//
#include <hip/hip_runtime.h>

#define NGAUSS 2048
#define NPIX   65536
#define WID    512.0f
#define HEI    512.0f

// ---------------- tiled path geometry ----------------
#define NTX     8            // tiles in x (64 px each)
#define NTY     8
#define NTILE   (NTX * NTY)  // 64 tiles
#define TSHIFT  6            // 64 px per tile
#define GCAP    2048         // max gaussians per tile list (worst case = all)
#define PCAP    2048         // max pixels per tile (uniform avg 1024, max ~1200)
#define TPB     256
#define NCHUNK  (PCAP / TPB) // 8 pixel chunks per tile
#define PREP_NB (NGAUSS / TPB)       // 8 blocks do gaussian prep
#define BIN_NB  32                   // 32 blocks do pixel binning
#define BIN_PPB (NPIX / BIN_NB)      // 2048 pixels per bin block
#define BIN_PPT (BIN_PPB / TPB)      // 8 pixels per thread

// sqrt of exp2-domain cutoff: w < 2^-27 dropped; error <= 2048*2^-27 = 1.5e-5
#define SQRT_CUT 5.2f

// workspace layout (bytes)
#define WS_PRM_OFF   0                         // 2048*3 float4 = 98304 B
#define WS_GCNT_OFF  98304                     // 64 u32
#define WS_PCNT_OFF  98560                     // 64 u32
#define WS_GLIST_OFF 98816                     // 64*2048 u32 = 524288 B
#define WS_PLIST_OFF (98816 + 524288)          // 64*2048 u32 = 524288 B
#define WS_NEED      (WS_PLIST_OFF + 524288)   // 1,147,392 B

// Per-gaussian packed params (3 x float4 = 48 B):
// p0 = (A, B, C, D) ; p1 = (E0, E1, r, g) ; p2 = (b, 0, 0, 0)
// dx = A*X + B*Y + E0 ; dy = C*X + D*Y + E1 ; w = exp2(-(dx^2+dy^2))
// A..E pre-scaled by K = sqrt(log2(e)) so exp(-q) == exp2(-q_scaled).

// ---- kernel 1 (fused setup): blocks 0..7 = gaussian prep + bbox binning,
//      blocks 8..39 = pixel->tile binning. Both use block-privatized LDS
//      histograms + ONE global range-reservation atomic per (block,tile)
//      (round-3's 100us lesson: never fan 64K atomics into 64 counters).
__global__ __launch_bounds__(256) void setup_kernel(
    const float2* __restrict__ x, const float* __restrict__ rgb,
    const float* __restrict__ mu, const float* __restrict__ scale,
    const float* __restrict__ angle, float4* __restrict__ prm,
    unsigned* __restrict__ gcount, unsigned* __restrict__ glist,
    unsigned* __restrict__ pcount, unsigned* __restrict__ plist)
{
    __shared__ unsigned lcnt[NTILE];
    __shared__ unsigned lbase[NTILE];

    const int tid = threadIdx.x;
    if (tid < NTILE) lcnt[tid] = 0u;

    if (blockIdx.x < PREP_NB) {
        // ---------------- gaussian prep path ----------------
        const int n = blockIdx.x * TPB + tid;

        const float MU_BORDER = 1.05f;
        const float S_MIN = 1.0f / 30.0f;
        const float S_MAX = 1.0f / 0.75f;
        const float PI_APPROX = 3.1416f;
        const float K = 1.2011224087864498f;  // sqrt(log2(e))

        float mx = tanhf(mu[2*n+0]) * MU_BORDER * (0.5f * WID);
        float my = tanhf(mu[2*n+1]) * MU_BORDER * (0.5f * HEI);
        float al = tanhf(angle[n]) * PI_APPROX;
        float c = cosf(al);
        float s = sinf(al);
        float S0 = 1.0f / (1.0f + expf(-scale[2*n+0])) * (S_MAX - S_MIN) + S_MIN;
        float S1 = 1.0f / (1.0f + expf(-scale[2*n+1])) * (S_MAX - S_MIN) + S_MIN;

        float A  =  S0 * c * K;
        float Bc = -(S0 * s * K);
        float C  =  S1 * s * K;
        float D  =  S1 * c * K;
        float E0 = -(A * mx + Bc * my);
        float E1 = -(C * mx + D  * my);

        float r = 1.0f / (1.0f + expf(-rgb[3*n+0]));
        float g = 1.0f / (1.0f + expf(-rgb[3*n+1]));
        float b = 1.0f / (1.0f + expf(-rgb[3*n+2]));

        prm[3*n + 0] = make_float4(A, Bc, C, D);
        prm[3*n + 1] = make_float4(E0, E1, r, g);
        prm[3*n + 2] = make_float4(b, 0.f, 0.f, 0.f);

        // conservative bbox of {q_scaled <= SQRT_CUT^2}: ellipse projections
        float i0 = 1.0f / S0, i1 = 1.0f / S1;
        float hx = (SQRT_CUT / K) * sqrtf(c*c*i0*i0 + s*s*i1*i1);
        float hy = (SQRT_CUT / K) * sqrtf(s*s*i0*i0 + c*c*i1*i1);
        float px = mx + 0.5f * WID;   // pixel-space center
        float py = my + 0.5f * HEI;

        int ix0 = (int)floorf(px - hx), ix1 = (int)floorf(px + hx);
        int iy0 = (int)floorf(py - hy), iy1 = (int)floorf(py + hy);
        int tx0 = max(0, ix0 >> TSHIFT), tx1 = min(NTX - 1, ix1 >> TSHIFT);
        int ty0 = max(0, iy0 >> TSHIFT), ty1 = min(NTY - 1, iy1 >> TSHIFT);

        __syncthreads();
        for (int ty = ty0; ty <= ty1; ++ty)
            for (int tx = tx0; tx <= tx1; ++tx)
                atomicAdd(&lcnt[ty * NTX + tx], 1u);
        __syncthreads();
        if (tid < NTILE) {
            lbase[tid] = atomicAdd(&gcount[tid], lcnt[tid]);  // chains of 8
            lcnt[tid] = 0u;
        }
        __syncthreads();
        for (int ty = ty0; ty <= ty1; ++ty)
            for (int tx = tx0; tx <= tx1; ++tx) {
                int t = ty * NTX + tx;
                unsigned slot = lbase[t] + atomicAdd(&lcnt[t], 1u);
                if (slot < GCAP) glist[t * GCAP + slot] = (unsigned)n;
            }
    } else {
        // ---------------- pixel binning path ----------------
        const int start = (blockIdx.x - PREP_NB) * BIN_PPB;
        __syncthreads();

        unsigned tcache[BIN_PPT];
        #pragma unroll
        for (int k = 0; k < BIN_PPT; ++k) {
            int b = start + k * TPB + tid;
            float2 p = x[b];
            int tx = min(NTX - 1, max(0, ((int)p.x) >> TSHIFT));
            int ty = min(NTY - 1, max(0, ((int)p.y) >> TSHIFT));
            unsigned t = (unsigned)(ty * NTX + tx);
            tcache[k] = t;
            atomicAdd(&lcnt[t], 1u);            // LDS atomic
        }
        __syncthreads();
        if (tid < NTILE) {
            lbase[tid] = atomicAdd(&pcount[tid], lcnt[tid]);  // chains of 32
            lcnt[tid] = 0u;
        }
        __syncthreads();
        #pragma unroll
        for (int k = 0; k < BIN_PPT; ++k) {
            int b = start + k * TPB + tid;
            unsigned t = tcache[k];
            unsigned slot = lbase[t] + atomicAdd(&lcnt[t], 1u);
            if (slot < PCAP) plist[t * PCAP + slot] = (unsigned)b;
        }
    }
}

// ---- kernel 2: per-tile splat; one thread = one pixel; plain stores ----
// Every pixel is in exactly one tile list (tile counts ~1150 << PCAP) and
// the chunk grid covers all slots, so every out[] element is written exactly
// once -> no atomics AND no d_out pre-zeroing needed.
__global__ __launch_bounds__(256) void splat_tile(
    const float2* __restrict__ x, const float4* __restrict__ prm,
    const unsigned* __restrict__ gcount, const unsigned* __restrict__ glist,
    const unsigned* __restrict__ pcount, const unsigned* __restrict__ plist,
    float* __restrict__ out)
{
    __shared__ float4 sg[TPB * 3];   // 12 KiB: one batch of gaussian params

    const int t     = blockIdx.x;
    const int tid   = threadIdx.x;
    const unsigned pcnt = min(pcount[t], (unsigned)PCAP);
    const unsigned base = blockIdx.y * TPB;
    if (base >= pcnt) return;                 // uniform exit, before barriers

    const bool valid = (base + tid) < pcnt;
    unsigned slot = base + (valid ? (unsigned)tid : 0u);
    unsigned pid  = plist[t * PCAP + slot];
    float2 p = x[pid];
    float X = p.x - 0.5f * WID;
    float Y = p.y - 0.5f * HEI;

    const unsigned gcnt = min(gcount[t], (unsigned)GCAP);
    float ar = 0.f, ag = 0.f, ab = 0.f;

    for (unsigned g0 = 0; g0 < gcnt; g0 += TPB) {
        __syncthreads();
        unsigned gi = g0 + tid;
        if (gi < gcnt) {
            unsigned n = glist[t * GCAP + gi];
            sg[3*tid + 0] = prm[3*n + 0];
            sg[3*tid + 1] = prm[3*n + 1];
            sg[3*tid + 2] = prm[3*n + 2];
        }
        __syncthreads();

        unsigned cnt = min((unsigned)TPB, gcnt - g0);
        #pragma unroll 4
        for (unsigned j = 0; j < cnt; ++j) {
            float4 c0 = sg[3*j + 0];
            float4 c1 = sg[3*j + 1];
            float4 c2 = sg[3*j + 2];
            float dx = fmaf(c0.x, X, fmaf(c0.y, Y, c1.x));
            float dy = fmaf(c0.z, X, fmaf(c0.w, Y, c1.y));
            float q  = fmaf(dx, dx, dy * dy);
            float w  = __builtin_amdgcn_exp2f(-q);
            ar = fmaf(w, c1.z, ar);
            ag = fmaf(w, c1.w, ag);
            ab = fmaf(w, c2.x, ab);
        }
    }

    if (valid) {                 // exactly one writer per pixel
        out[3*pid + 0] = ar;
        out[3*pid + 1] = ag;
        out[3*pid + 2] = ab;
    }
}

// ---------------- fallback: round-2 flat kernel (ws too small) ----------------
#define NSLICE 16
#define GPB    (NGAUSS / NSLICE)
#define PPB    512

__global__ __launch_bounds__(256) void splat_flat(
    const float2* __restrict__ x, const float* __restrict__ rgb,
    const float* __restrict__ mu, const float* __restrict__ scale,
    const float* __restrict__ angle, float* __restrict__ out)
{
    __shared__ float4 sh4[GPB * 2];
    __shared__ float  shb[GPB];

    const int slice = blockIdx.x & (NSLICE - 1);
    const int pg    = blockIdx.x >> 4;
    const int tid   = threadIdx.x;

    if (tid < GPB) {
        const float MU_BORDER = 1.05f;
        const float S_MIN = 1.0f / 30.0f;
        const float S_MAX = 1.0f / 0.75f;
        const float PI_APPROX = 3.1416f;
        const float K = 1.2011224087864498f;

        int n = slice * GPB + tid;
        float mx = tanhf(mu[2*n+0]) * MU_BORDER * (0.5f * WID);
        float my = tanhf(mu[2*n+1]) * MU_BORDER * (0.5f * HEI);
        float al = tanhf(angle[n]) * PI_APPROX;
        float c = cosf(al);
        float s = sinf(al);
        float S0 = 1.0f / (1.0f + expf(-scale[2*n+0])) * (S_MAX - S_MIN) + S_MIN;
        float S1 = 1.0f / (1.0f + expf(-scale[2*n+1])) * (S_MAX - S_MIN) + S_MIN;
        float A  =  S0 * c * K;
        float Bc = -(S0 * s * K);
        float C  =  S1 * s * K;
        float D  =  S1 * c * K;
        sh4[2*tid + 0] = make_float4(A, Bc, C, D);
        sh4[2*tid + 1] = make_float4(-(A * mx + Bc * my), -(C * mx + D * my),
                                     1.0f / (1.0f + expf(-rgb[3*n+0])),
                                     1.0f / (1.0f + expf(-rgb[3*n+1])));
        shb[tid] = 1.0f / (1.0f + expf(-rgb[3*n+2]));
    }
    __syncthreads();

    const int t0 = pg * PPB + tid;
    const int t1 = t0 + TPB;
    float2 xy0 = x[t0];
    float2 xy1 = x[t1];
    float X0 = xy0.x - 0.5f * WID, Y0 = xy0.y - 0.5f * HEI;
    float X1 = xy1.x - 0.5f * WID, Y1 = xy1.y - 0.5f * HEI;

    float ar0 = 0.f, ag0 = 0.f, ab0 = 0.f;
    float ar1 = 0.f, ag1 = 0.f, ab1 = 0.f;
    #pragma unroll 4
    for (int j = 0; j < GPB; ++j) {
        float4 c0 = sh4[2*j + 0];
        float4 c1 = sh4[2*j + 1];
        float bb  = shb[j];
        float dx0 = fmaf(c0.x, X0, fmaf(c0.y, Y0, c1.x));
        float dy0 = fmaf(c0.z, X0, fmaf(c0.w, Y0, c1.y));
        float w0  = __builtin_amdgcn_exp2f(-fmaf(dx0, dx0, dy0 * dy0));
        float dx1 = fmaf(c0.x, X1, fmaf(c0.y, Y1, c1.x));
        float dy1 = fmaf(c0.z, X1, fmaf(c0.w, Y1, c1.y));
        float w1  = __builtin_amdgcn_exp2f(-fmaf(dx1, dx1, dy1 * dy1));
        ar0 = fmaf(w0, c1.z, ar0); ag0 = fmaf(w0, c1.w, ag0); ab0 = fmaf(w0, bb, ab0);
        ar1 = fmaf(w1, c1.z, ar1); ag1 = fmaf(w1, c1.w, ag1); ab1 = fmaf(w1, bb, ab1);
    }

    atomicAdd(&out[3*t0 + 0], ar0);
    atomicAdd(&out[3*t0 + 1], ag0);
    atomicAdd(&out[3*t0 + 2], ab0);
    atomicAdd(&out[3*t1 + 0], ar1);
    atomicAdd(&out[3*t1 + 1], ag1);
    atomicAdd(&out[3*t1 + 2], ab1);
}

extern "C" void kernel_launch(void* const* d_in, const int* in_sizes, int n_in,
                              void* d_out, int out_size, void* d_ws, size_t ws_size,
                              hipStream_t stream) {
    const float* x     = (const float*)d_in[0];  // [B,2]
    const float* rgb   = (const float*)d_in[1];  // [N,3]
    const float* mu    = (const float*)d_in[2];  // [N,2]
    const float* scale = (const float*)d_in[3];  // [N,2]
    const float* angle = (const float*)d_in[4];  // [N]

    if (ws_size >= (size_t)WS_NEED && d_ws != nullptr) {
        char* ws = (char*)d_ws;
        float4*   prm    = (float4*)(ws + WS_PRM_OFF);
        unsigned* gcount = (unsigned*)(ws + WS_GCNT_OFF);
        unsigned* pcount = (unsigned*)(ws + WS_PCNT_OFF);
        unsigned* glist  = (unsigned*)(ws + WS_GLIST_OFF);
        unsigned* plist  = (unsigned*)(ws + WS_PLIST_OFF);

        // zero the two count arrays (contiguous 512 B); d_out needs no
        // zeroing on this path (every pixel plain-stored exactly once)
        hipMemsetAsync(ws + WS_GCNT_OFF, 0, 512, stream);

        hipLaunchKernelGGL(setup_kernel, dim3(PREP_NB + BIN_NB), dim3(TPB), 0, stream,
                           (const float2*)x, rgb, mu, scale, angle,
                           prm, gcount, glist, pcount, plist);
        hipLaunchKernelGGL(splat_tile, dim3(NTILE, NCHUNK), dim3(TPB), 0, stream,
                           (const float2*)x, prm, gcount, glist, pcount, plist,
                           (float*)d_out);
    } else {
        // harness poisons d_out with 0xAA — fallback accumulates, so zero it
        hipMemsetAsync(d_out, 0, (size_t)out_size * sizeof(float), stream);
        hipLaunchKernelGGL(splat_flat, dim3(NPIX / PPB * NSLICE), dim3(TPB), 0, stream,
                           (const float2*)x, rgb, mu, scale, angle, (float*)d_out);
    }
}